// Round 7
// baseline (41.014 us; speedup 1.0000x reference)
//
#include <hip/hip_runtime.h>
#include <hip/hip_bf16.h>

#define B_   32
#define N_   128
#define AH_  512
#define AW_  512
#define LCAP 128   // worst case: all boxes active on this row pair

// compiler-only reordering fence; one wave's DS ops execute in issue order
#define CFENCE() asm volatile("" ::: "memory")

// ---------------------------------------------------------------------------
// 128 threads = 2 INDEPENDENT waves (no __syncthreads). Each wave owns TWO
// consecutive rows {y0,y0+1}. KEY CHANGE vs R6: the rasterized mask lives in
// REGISTERS val[2][8] (pixel h*64+lane), not LDS. Boxes update it with
// cndmask selects in index order (last-wins). LDS holds only the compacted
// box list (pk: x1|x2<<10|act<<20, wt: {x1m,x2m,rowv0,rowv1}), read with
// 1-deep prefetch; readfirstlane makes the chunk loop bounds scalar so
// untouched chunks cost 2 scalar compares. No mask zero/write/read chains,
// no CFENCE round trips -> latency off the critical path.
// ---------------------------------------------------------------------------
__global__ __launch_bounds__(128, 8) void row_bce_kernel(
    const float* __restrict__ att,
    const float* __restrict__ bboxs,
    const int*   __restrict__ img_h_p,
    const int*   __restrict__ img_w_p,
    float*       __restrict__ wave_sums)
{
    const int t    = threadIdx.x;
    const int lane = t & 63;
    const int wid  = t >> 6;                    // 0..1
    const int task = (blockIdx.x << 1) | wid;   // 0..8191
    const int b    = task >> 8;                 // 256 tasks per image
    const int y0   = (task & 255) << 1;         // rows y0, y0+1

    __shared__ unsigned s_pk[2][LCAP];
    __shared__ float4   s_wt[2][LCAP];

    const float fw  = (float)(*img_w_p);
    const float fh  = (float)(*img_h_p);
    const float sxs = (float)AW_ / fw;
    const float sys = (float)AH_ / fh;

    // ---- box geometry, once per wave (boxes lane and lane+64) ----
    bool     act_any[2];
    unsigned pk[2];
    float4   wt[2];
    #pragma unroll
    for (int k = 0; k < 2; ++k) {
        const int n = lane + 64 * k;
        const float* bp = bboxs + ((size_t)b * N_ + n) * 5;
        const float c0 = bp[0], c1 = bp[1], c2 = bp[2], c3 = bp[3], lab = bp[4];
        const bool valid = (lab != -1.0f) && (c0 <= fw) && (c1 <= fh)
                                          && (c2 <= fw) && (c3 <= fh);
        const float bx1 = c0 * sxs, by1 = c1 * sys;
        const float bx2 = c2 * sxs, by2 = c3 * sys;
        const float fx1 = floorf(bx1), fy1 = floorf(by1);
        const float x1m = fx1 + 1.0f - bx1;
        const float y1m = fy1 + 1.0f - by1;
        const float x2m = bx2 - floorf(bx2);
        const float y2m = by2 - floorf(by2);
        const int x1 = (int)fmaxf(fx1, 0.0f);
        const int y1 = (int)fmaxf(fy1, 0.0f);
        const int x2 = (int)fminf(ceilf(bx2) + 1.0f, (float)AW_);
        const int y2 = (int)fminf(ceilf(by2) + 1.0f, (float)AH_);
        int   ab = 0;
        float rv0 = 1.0f, rv1 = 1.0f;
        #pragma unroll
        for (int r = 0; r < 2; ++r) {
            const int y = y0 + r;
            const bool a = valid && (y >= y1) && (y < y2);
            ab |= a ? (1 << r) : 0;
            const float rw = ((y == y1)     ? y1m : 1.0f)
                           * ((y == y2 - 1) ? y2m : 1.0f);
            if (r == 0) rv0 = rw; else rv1 = rw;
        }
        act_any[k] = (ab != 0);
        pk[k] = (unsigned)x1 | ((unsigned)x2 << 10) | ((unsigned)ab << 20);
        wt[k] = make_float4(x1m, x2m, rv0, rv1);
    }

    // ---- order-preserving compaction into the wave-private LDS list ----
    const unsigned long long ltm = (1ull << lane) - 1ull;
    const unsigned long long bal0 = __ballot(act_any[0]);
    const unsigned long long bal1 = __ballot(act_any[1]);
    const int cnt0 = __popcll(bal0);
    const int cnt  = cnt0 + __popcll(bal1);
    if (act_any[0]) {
        const int s = __popcll(bal0 & ltm);
        s_pk[wid][s] = pk[0];
        s_wt[wid][s] = wt[0];
    }
    if (act_any[1]) {
        const int s = cnt0 + __popcll(bal1 & ltm);
        s_pk[wid][s] = pk[1];
        s_wt[wid][s] = wt[1];
    }
    CFENCE();   // list writes precede list reads (same-wave in-order DS pipe)

    // ---- register rasterize: val[r][h] = mask value at pixel h*64+lane ----
    float val[2][8];
    #pragma unroll
    for (int r = 0; r < 2; ++r)
        #pragma unroll
        for (int h = 0; h < 8; ++h) val[r][h] = 0.0f;

    if (cnt > 0) {
        unsigned pkc = s_pk[wid][0];
        float4   wtc = s_wt[wid][0];
        for (int i = 0; i < cnt; ++i) {
            const unsigned pki = pkc;
            const float4   wti = wtc;
            if (i + 1 < cnt) {              // 1-deep prefetch
                pkc = s_pk[wid][i + 1];
                wtc = s_wt[wid][i + 1];
            }
            const unsigned pks = __builtin_amdgcn_readfirstlane(pki);
            const int e1 = (int)(pks & 1023u);
            const int e2 = (int)((pks >> 10) & 1023u);
            const int ab = (int)(pks >> 20);
            const int h1 = e1 >> 6;
            const int h2 = (e2 - 1) >> 6;
            #pragma unroll
            for (int h = 0; h < 8; ++h) {
                if (h >= h1 && h <= h2) {   // scalar guard: untouched chunks skipped
                    const int  x   = (h << 6) + lane;
                    const bool inb = (x >= e1) & (x < e2);
                    const float edge = ((x == e1)     ? wti.x : 1.0f)
                                     * ((x == e2 - 1) ? wti.y : 1.0f);
                    if (ab & 1) val[0][h] = inb ? wti.z * edge : val[0][h];
                    if (ab & 2) val[1][h] = inb ? wti.w * edge : val[1][h];
                }
            }
        }
    }

    // ---- BCE: att dword loads match the h*64+lane mapping; per-chunk gate ----
    const float* prow = att + ((size_t)b * AH_ + y0) * AW_;
    float acc = 0.0f;
    #pragma unroll
    for (int r = 0; r < 2; ++r) {
        #pragma unroll
        for (int h = 0; h < 8; ++h) {
            const float p  = prow[r * AW_ + (h << 6) + lane];
            const float mv = val[r][h];
            const float l1 = __logf(1.0f - p);   // p in [1e-4,1-1e-4]: no clamp
            if (__any(mv != 0.0f)) {
                acc += l1 + mv * (__logf(p) - l1);
            } else {
                acc += l1;
            }
        }
    }

    // ---- wave reduction -> per-task partial ----
    #pragma unroll
    for (int off = 32; off; off >>= 1) acc += __shfl_down(acc, off, 64);
    if (lane == 0) wave_sums[task] = acc;
}

// ---------------------------------------------------------------------------
// Fused tail: per-image reduce of 256 task partials + any_valid gate +
// batch mean. One block, 1024 threads (32 workers per image).
// ---------------------------------------------------------------------------
__global__ __launch_bounds__(1024) void final_kernel(
    const float* __restrict__ bboxs,
    const int*   __restrict__ img_h_p,
    const int*   __restrict__ img_w_p,
    const float* __restrict__ wave_sums,
    float*       __restrict__ out)
{
    const int t = threadIdx.x;
    const int b = t >> 5;        // image 0..31
    const int j = t & 31;        // worker within image

    __shared__ float s_sum[1024];
    __shared__ int   s_any[1024];
    __shared__ float s_loss[B_];

    float s = 0.0f;
    #pragma unroll
    for (int k = 0; k < 8; ++k) s += wave_sums[b * 256 + j + 32 * k];
    s_sum[t] = s;

    const float fw = (float)(*img_w_p);
    const float fh = (float)(*img_h_p);
    int av = 0;
    const float* bp = bboxs + (size_t)b * N_ * 5;
    #pragma unroll
    for (int n = j * 4; n < j * 4 + 4; ++n) {
        const float c0 = bp[n * 5 + 0];
        const float c1 = bp[n * 5 + 1];
        const float c2 = bp[n * 5 + 2];
        const float c3 = bp[n * 5 + 3];
        const float lab = bp[n * 5 + 4];
        av |= ((lab != -1.0f) && (c0 <= fw) && (c1 <= fh)
                              && (c2 <= fw) && (c3 <= fh)) ? 1 : 0;
    }
    s_any[t] = av;
    __syncthreads();

    if (j == 0) {
        float sum = 0.0f;
        int anyv = 0;
        for (int k = 0; k < 32; ++k) {
            sum  += s_sum[b * 32 + k];
            anyv |= s_any[b * 32 + k];
        }
        s_loss[b] = anyv ? (-sum * (1.0f / (float)(AH_ * AW_))) : 0.0f;
    }
    __syncthreads();

    if (t == 0) {
        float total = 0.0f;
        for (int k = 0; k < B_; ++k) total += s_loss[k];
        out[0] = total * (1.0f / (float)B_);
    }
}

extern "C" void kernel_launch(void* const* d_in, const int* in_sizes, int n_in,
                              void* d_out, int out_size, void* d_ws, size_t ws_size,
                              hipStream_t stream)
{
    const float* att   = (const float*)d_in[0];   // (32,1,512,512) f32
    const float* bboxs = (const float*)d_in[1];   // (32,128,5) f32
    const int*   img_h = (const int*)d_in[2];     // scalar
    const int*   img_w = (const int*)d_in[3];     // scalar
    float* out = (float*)d_out;
    float* wave_sums = (float*)d_ws;              // 8192 floats (32 KB)

    row_bce_kernel<<<B_ * AH_ / 4, 128, 0, stream>>>(att, bboxs, img_h, img_w, wave_sums);
    final_kernel<<<1, 1024, 0, stream>>>(bboxs, img_h, img_w, wave_sums, out);
}

// Round 8
// 31.982 us; speedup vs baseline: 1.2824x; 1.2824x over previous
//
#include <hip/hip_runtime.h>
#include <hip/hip_bf16.h>

#define B_   32
#define N_   128
#define AH_  512
#define AW_  512
#define LCAP 64    // per-chunk list capacity (one 64-box ballot chunk)

// compiler-only reordering fence; one wave's DS ops execute in issue order
#define CFENCE() asm volatile("" ::: "memory")

// ---------------------------------------------------------------------------
// 128 threads = 2 INDEPENDENT waves (no __syncthreads). Each wave owns TWO
// consecutive rows {y0,y0+1}; LDS per wave: compacted box list (pk: x1 |
// x2<<10 | ab<<20, wt: {x1m,x2m,rv0,rv1}) + [2][512] f32 mask.
//
// R8 changes vs R6 (tied-best 29.4us): the raster inner loop is slimmed.
//  - readfirstlane(pk) -> e1/e2/ab in SGPRs: uniform loop control
//  - span writes ONLY the interior value (no per-pixel edge cmps/muls);
//    ab==3 fast path (97% of boxes) = 2 unconditional ds_writes where the
//    row1 write folds to an offset:2048 immediate on the same address
//  - edge pixels fixed AFTER the span by lanes 0..3 (2 rows x left/right);
//    same-wave DS pipe is in-order, so later fixup writes win, and box i+1's
//    span (later instructions) overwrites box i's fixup where they overlap
// ---------------------------------------------------------------------------
__global__ __launch_bounds__(128) void row_bce_kernel(
    const float* __restrict__ att,
    const float* __restrict__ bboxs,
    const int*   __restrict__ img_h_p,
    const int*   __restrict__ img_w_p,
    float*       __restrict__ wave_sums)
{
    const int t    = threadIdx.x;
    const int lane = t & 63;
    const int wid  = t >> 6;                    // 0..1
    const int task = (blockIdx.x << 1) | wid;   // 0..8191
    const int b    = task >> 8;                 // 256 tasks per image
    const int y0   = (task & 255) << 1;         // rows y0, y0+1

    __shared__ unsigned s_pk[2][LCAP];          // x1 | x2<<10 | ab<<20
    __shared__ float4   s_wt[2][LCAP];          // {x1m, x2m, rv0, rv1}
    __shared__ float    s_mask[2][2][AW_];      // [wid][row][x]

    const float fw  = (float)(*img_w_p);
    const float fh  = (float)(*img_h_p);
    const float sxs = (float)AW_ / fw;
    const float sys = (float)AH_ / fh;

    // ---- hoisted attention loads (independent of everything below) ----
    const float4* p4 = (const float4*)(att + ((size_t)b * AH_ + y0) * AW_);
    float4 P[2][2];
    #pragma unroll
    for (int r = 0; r < 2; ++r)
        #pragma unroll
        for (int h = 0; h < 2; ++h)
            P[r][h] = p4[r * 128 + h * 64 + lane];

    // ---- box geometry, once per wave (boxes lane and lane+64) ----
    bool     act_any[2];
    unsigned pk[2];
    float4   wt[2];
    #pragma unroll
    for (int k = 0; k < 2; ++k) {
        const int n = lane + 64 * k;
        const float* bp = bboxs + ((size_t)b * N_ + n) * 5;
        const float c0 = bp[0], c1 = bp[1], c2 = bp[2], c3 = bp[3], lab = bp[4];
        const bool valid = (lab != -1.0f) && (c0 <= fw) && (c1 <= fh)
                                          && (c2 <= fw) && (c3 <= fh);
        const float bx1 = c0 * sxs, by1 = c1 * sys;
        const float bx2 = c2 * sxs, by2 = c3 * sys;
        const float fx1 = floorf(bx1), fy1 = floorf(by1);
        const float x1m = fx1 + 1.0f - bx1;
        const float y1m = fy1 + 1.0f - by1;
        const float x2m = bx2 - floorf(bx2);
        const float y2m = by2 - floorf(by2);
        const int x1 = (int)fmaxf(fx1, 0.0f);
        const int y1 = (int)fmaxf(fy1, 0.0f);
        const int x2 = (int)fminf(ceilf(bx2) + 1.0f, (float)AW_);
        const int y2 = (int)fminf(ceilf(by2) + 1.0f, (float)AH_);
        int   ab = 0;
        float rv0 = 1.0f, rv1 = 1.0f;
        #pragma unroll
        for (int r = 0; r < 2; ++r) {
            const int y = y0 + r;
            const bool a = valid && (y >= y1) && (y < y2);
            ab |= a ? (1 << r) : 0;
            const float rw = ((y == y1)     ? y1m : 1.0f)
                           * ((y == y2 - 1) ? y2m : 1.0f);
            if (r == 0) rv0 = rw; else rv1 = rw;
        }
        act_any[k] = (ab != 0) && (x1 < x2);
        pk[k] = (unsigned)x1 | ((unsigned)x2 << 10) | ((unsigned)ab << 20);
        wt[k] = make_float4(x1m, x2m, rv0, rv1);
    }

    const unsigned long long ltm  = (1ull << lane) - 1ull;
    const unsigned long long bal0 = __ballot(act_any[0]);
    const unsigned long long bal1 = __ballot(act_any[1]);
    const bool have = (bal0 | bal1) != 0ull;

    float* m0 = s_mask[wid][0];                 // row1 = m0 + 512 (offset:2048)
    float4* mrow4 = (float4*)m0;

    if (have) {
        // zero both mask rows: 4x ds_write_b128 per lane
        const float4 z = make_float4(0.f, 0.f, 0.f, 0.f);
        #pragma unroll
        for (int q = 0; q < 4; ++q) mrow4[lane + 64 * q] = z;
        CFENCE();

        // ---- two 64-box chunks in index order; list buffer reused ----
        #pragma unroll
        for (int k = 0; k < 2; ++k) {
            const unsigned long long bal = (k == 0) ? bal0 : bal1;
            const int cnt = __popcll(bal);
            if (cnt == 0) continue;
            if (k == 0 ? act_any[0] : act_any[1]) {
                const int s = __popcll(bal & ltm);
                s_pk[wid][s] = pk[k];
                s_wt[wid][s] = wt[k];
            }
            CFENCE();   // compaction writes precede list reads (in-order DS)

            unsigned pkc = s_pk[wid][0];
            float4   wtc = s_wt[wid][0];
            for (int i = 0; i < cnt; ++i) {
                const unsigned pki = pkc;
                const float4   wti = wtc;
                if (i + 1 < cnt) {          // 1-deep prefetch
                    pkc = s_pk[wid][i + 1];
                    wtc = s_wt[wid][i + 1];
                }
                const unsigned pks = (unsigned)__builtin_amdgcn_readfirstlane((int)pki);
                const int e1 = (int)(pks & 1023u);
                const int e2 = (int)((pks >> 10) & 1023u);
                const int ab = (int)(pks >> 20);

                // interior span (constant value per row; no edge math)
                if (ab == 3) {
                    for (int x = e1 + lane; x < e2; x += 64) {
                        m0[x]       = wti.z;
                        m0[x + 512] = wti.w;   // same addr + offset:2048
                    }
                } else if (ab == 1) {
                    for (int x = e1 + lane; x < e2; x += 64) m0[x] = wti.z;
                } else {
                    for (int x = e1 + lane; x < e2; x += 64) m0[x + 512] = wti.w;
                }

                // edge fixup: lanes 0..3 = (row r, side s); later DS ops win
                if (lane < 4) {
                    const int r    = lane >> 1;
                    const int side = lane & 1;
                    if ((ab >> r) & 1) {
                        const float rv = r ? wti.w : wti.z;
                        if (side == 0) {
                            float v = rv * wti.x;
                            if (e1 == e2 - 1) v *= wti.y;
                            m0[r * 512 + e1] = v;
                        } else if (e2 - 1 > e1) {
                            m0[r * 512 + e2 - 1] = rv * wti.y;
                        }
                    }
                }
            }
            CFENCE();   // raster reads precede next chunk's compaction writes
        }
    }

    // ---- BCE over 2 rows (p in [1e-4,1-1e-4]: no clamps needed) ----
    float acc = 0.0f;
    #pragma unroll
    for (int r = 0; r < 2; ++r) {
        #pragma unroll
        for (int h = 0; h < 2; ++h) {
            const float4 p = P[r][h];
            float4 m = make_float4(0.f, 0.f, 0.f, 0.f);
            if (have) m = mrow4[r * 128 + h * 64 + lane];
            const float pv[4] = {p.x, p.y, p.z, p.w};
            const float mv[4] = {m.x, m.y, m.z, m.w};
            const bool nz = (m.x != 0.f) | (m.y != 0.f)
                          | (m.z != 0.f) | (m.w != 0.f);
            if (__any(nz)) {
                #pragma unroll
                for (int j = 0; j < 4; ++j) {
                    const float lp = __logf(pv[j]);
                    const float l1 = __logf(1.0f - pv[j]);
                    acc += l1 + mv[j] * (lp - l1);
                }
            } else {
                #pragma unroll
                for (int j = 0; j < 4; ++j)
                    acc += __logf(1.0f - pv[j]);
            }
        }
    }

    // ---- wave reduction -> per-task partial ----
    #pragma unroll
    for (int off = 32; off; off >>= 1) acc += __shfl_down(acc, off, 64);
    if (lane == 0) wave_sums[task] = acc;
}

// ---------------------------------------------------------------------------
// Fused tail: per-image reduce of 256 task partials + any_valid gate +
// batch mean. One block, 1024 threads (32 workers per image).
// ---------------------------------------------------------------------------
__global__ __launch_bounds__(1024) void final_kernel(
    const float* __restrict__ bboxs,
    const int*   __restrict__ img_h_p,
    const int*   __restrict__ img_w_p,
    const float* __restrict__ wave_sums,
    float*       __restrict__ out)
{
    const int t = threadIdx.x;
    const int b = t >> 5;        // image 0..31
    const int j = t & 31;        // worker within image

    __shared__ float s_sum[1024];
    __shared__ int   s_any[1024];
    __shared__ float s_loss[B_];

    float s = 0.0f;
    #pragma unroll
    for (int k = 0; k < 8; ++k) s += wave_sums[b * 256 + j + 32 * k];
    s_sum[t] = s;

    const float fw = (float)(*img_w_p);
    const float fh = (float)(*img_h_p);
    int av = 0;
    const float* bp = bboxs + (size_t)b * N_ * 5;
    #pragma unroll
    for (int n = j * 4; n < j * 4 + 4; ++n) {
        const float c0 = bp[n * 5 + 0];
        const float c1 = bp[n * 5 + 1];
        const float c2 = bp[n * 5 + 2];
        const float c3 = bp[n * 5 + 3];
        const float lab = bp[n * 5 + 4];
        av |= ((lab != -1.0f) && (c0 <= fw) && (c1 <= fh)
                              && (c2 <= fw) && (c3 <= fh)) ? 1 : 0;
    }
    s_any[t] = av;
    __syncthreads();

    if (j == 0) {
        float sum = 0.0f;
        int anyv = 0;
        for (int k = 0; k < 32; ++k) {
            sum  += s_sum[b * 32 + k];
            anyv |= s_any[b * 32 + k];
        }
        s_loss[b] = anyv ? (-sum * (1.0f / (float)(AH_ * AW_))) : 0.0f;
    }
    __syncthreads();

    if (t == 0) {
        float total = 0.0f;
        for (int k = 0; k < B_; ++k) total += s_loss[k];
        out[0] = total * (1.0f / (float)B_);
    }
}

extern "C" void kernel_launch(void* const* d_in, const int* in_sizes, int n_in,
                              void* d_out, int out_size, void* d_ws, size_t ws_size,
                              hipStream_t stream)
{
    const float* att   = (const float*)d_in[0];   // (32,1,512,512) f32
    const float* bboxs = (const float*)d_in[1];   // (32,128,5) f32
    const int*   img_h = (const int*)d_in[2];     // scalar
    const int*   img_w = (const int*)d_in[3];     // scalar
    float* out = (float*)d_out;
    float* wave_sums = (float*)d_ws;              // 8192 floats (32 KB)

    row_bce_kernel<<<B_ * AH_ / 4, 128, 0, stream>>>(att, bboxs, img_h, img_w, wave_sums);
    final_kernel<<<1, 1024, 0, stream>>>(bboxs, img_h, img_w, wave_sums, out);
}